// Round 1
// baseline (45.854 us; speedup 1.0000x reference)
//
#include <hip/hip_runtime.h>

// Depthwise separable blur, upfirdn2d(x, outer([1,3,3,1])/8^2*4, pad=(2,1)).
// Separable weights w = [0.25, 0.75, 0.75, 0.25], taps at offsets {-2,-1,0,+1},
// zero padding. Kernel is symmetric so true-conv flip is identity.

#define PH 64           // plane height
#define PW 64           // plane width
#define LDW 68          // LDS row stride (floats): keeps float4 16B-aligned,
                        // bank aliasing <= 2-way (free on CDNA4)

__global__ __launch_bounds__(256) void blur_sep_kernel(
    const float* __restrict__ x, float* __restrict__ out) {
    __shared__ float s_in[PH * LDW];
    __shared__ float s_tmp[PH * LDW];

    const int plane = blockIdx.x;
    const int t = threadIdx.x;

    const float* __restrict__ src = x + (size_t)plane * (PH * PW);
    float* __restrict__ dst = out + (size_t)plane * (PH * PW);

    // ---- Phase 1: global -> LDS, 4096 floats = 1024 float4, coalesced ----
    #pragma unroll
    for (int k = 0; k < 4; ++k) {
        const int f = t + k * 256;          // float4 index in plane
        const float4 v = reinterpret_cast<const float4*>(src)[f];
        const int y = f >> 4;               // (f*4) / 64
        const int x0 = (f & 15) << 2;       // (f*4) % 64
        float4* p = reinterpret_cast<float4*>(&s_in[y * LDW + x0]);
        *p = v;
    }
    __syncthreads();

    // ---- Phase 2: horizontal pass (row r, 16-px segment per thread) ----
    {
        const int r = t >> 2;               // row 0..63
        const int xseg = (t & 3) << 4;      // segment start 0,16,32,48
        const float* __restrict__ row = &s_in[r * LDW];
        float* __restrict__ trow = &s_tmp[r * LDW];
        #pragma unroll
        for (int i = 0; i < 16; ++i) {
            const int xx = xseg + i;
            const float a = (xx >= 2)      ? row[xx - 2] : 0.0f;
            const float b = (xx >= 1)      ? row[xx - 1] : 0.0f;
            const float c = row[xx];
            const float d = (xx + 1 < PW)  ? row[xx + 1] : 0.0f;
            trow[xx] = 0.25f * (a + d) + 0.75f * (b + c);
        }
    }
    __syncthreads();

    // ---- Phase 3: vertical pass fused with float4 store ----
    #pragma unroll
    for (int k = 0; k < 4; ++k) {
        const int f = t + k * 256;
        const int y = f >> 4;
        const int x0 = (f & 15) << 2;
        float acc0 = 0.f, acc1 = 0.f, acc2 = 0.f, acc3 = 0.f;
        #pragma unroll
        for (int i = 0; i < 4; ++i) {
            const int yy = y + i - 2;
            if (yy >= 0 && yy < PH) {
                const float wgt = (i == 0 || i == 3) ? 0.25f : 0.75f;
                const float* __restrict__ trow = &s_tmp[yy * LDW + x0];
                acc0 += wgt * trow[0];
                acc1 += wgt * trow[1];
                acc2 += wgt * trow[2];
                acc3 += wgt * trow[3];
            }
        }
        float4 v;
        v.x = acc0; v.y = acc1; v.z = acc2; v.w = acc3;
        reinterpret_cast<float4*>(dst)[f] = v;
    }
}

extern "C" void kernel_launch(void* const* d_in, const int* in_sizes, int n_in,
                              void* d_out, int out_size, void* d_ws, size_t ws_size,
                              hipStream_t stream) {
    const float* x = (const float*)d_in[0];
    float* out = (float*)d_out;
    const int nplanes = in_sizes[0] / (PH * PW);   // 16*512 = 8192
    blur_sep_kernel<<<nplanes, 256, 0, stream>>>(x, out);
}